// Round 2
// baseline (479.071 us; speedup 1.0000x reference)
//
#include <hip/hip_runtime.h>
#include <math.h>

#define S 512
#define B 128
#define T 256
#define NTH 256

typedef _Float16 h2 __attribute__((ext_vector_type(2)));
typedef _Float16 h8 __attribute__((ext_vector_type(8)));

#if __has_builtin(__builtin_amdgcn_fdot2)
#define FDOT2(a, b, c) __builtin_amdgcn_fdot2((a), (b), (c), false)
#else
#define FDOT2(a, b, c) fmaf((float)(a)[0], (float)(b)[0], fmaf((float)(a)[1], (float)(b)[1], (c)))
#endif

#define AS1 __attribute__((address_space(1)))
#define AS3 __attribute__((address_space(3)))

// LDS-drain barrier only (prefetch ring stays in flight across it — counted vmcnt elsewhere)
#define BAR() do { asm volatile("s_waitcnt lgkmcnt(0)" ::: "memory"); __builtin_amdgcn_s_barrier(); } while (0)

// ---- DPP wave64 max reduction (~12 VALU instrs vs 6 dependent ds_bpermute) ----
template<int CTRL, int RM>
__device__ __forceinline__ float dppmax(float x) {
    int xi = __builtin_bit_cast(int, x);
    int yi = __builtin_amdgcn_update_dpp(xi, xi, CTRL, RM, 0xf, false); // bound_ctrl=0: invalid lanes keep old(=x), max no-op
    return fmaxf(x, __builtin_bit_cast(float, yi));
}
__device__ __forceinline__ float wave_max_bcast(float x) {
    x = dppmax<0x111, 0xf>(x);  // row_shr:1
    x = dppmax<0x112, 0xf>(x);  // row_shr:2
    x = dppmax<0x114, 0xf>(x);  // row_shr:4
    x = dppmax<0x118, 0xf>(x);  // row_shr:8
    x = dppmax<0x142, 0xa>(x);  // row_bcast:15
    x = dppmax<0x143, 0xc>(x);  // row_bcast:31  -> lane 63 has wave max
    return __builtin_bit_cast(float, __builtin_amdgcn_readlane(__builtin_bit_cast(int, x), 63));
}

__global__ __launch_bounds__(NTH, 1) void crf_fwd(
    const float* __restrict__ feats,
    const int*   __restrict__ tags,
    const int*   __restrict__ mask,
    const float* __restrict__ start_t,
    const float* __restrict__ end_t,
    const float* __restrict__ trans,
    float*       __restrict__ out)
{
    const int b    = blockIdx.x;
    const int j    = threadIdx.x;     // output column 0..255 (T == NTH)
    const int lane = j & 63;
    const int w    = j >> 6;          // wave 0..3

    __shared__ __attribute__((aligned(16))) _Float16 pl[T];
    __shared__ float ftile[4][T];                       // feats prefetch ring
    __shared__ int   msk[S];
    __shared__ __attribute__((aligned(16))) float redmax[2][4];
    __shared__ float redg[4], redm[4];

    // ---- prime prefetch ring with feats tiles t=1..3 (land during init)
    #pragma unroll
    for (int tn = 1; tn <= 3; ++tn) {
        const float* src = feats + ((size_t)tn * B + b) * T + j;
        __builtin_amdgcn_global_load_lds((const AS1 void*)src,
                                         (AS3 void*)&ftile[tn & 3][j], 4, 0, 0);
    }

    // ---- small per-thread loads
    const float endj = end_t[j];
    float vv = start_t[j] + feats[(size_t)b * T + j];   // t=0
    msk[j]       = mask[j * B + b];
    msk[j + T]   = mask[(j + T) * B + b];

    // ---- gold-score terms: two time steps per thread
    float gterm = 0.f, mcnt = 0.f;
    #pragma unroll
    for (int c = 0; c < 2; ++c) {
        const int t  = j + c * T;
        const int tg = tags[t * B + b];
        const int m  = mask[t * B + b];
        const float emit = feats[((size_t)t * B + b) * T + tg];
        mcnt += (float)m;
        if (t == 0) {
            gterm += start_t[tg] + emit;
        } else {
            gterm += m ? (emit + trans[tags[(t - 1) * B + b] * T + tg]) : 0.f;
        }
    }
    #pragma unroll
    for (int o = 32; o > 0; o >>= 1) {
        gterm += __shfl_down(gterm, o, 64);
        mcnt  += __shfl_down(mcnt, o, 64);
    }
    if (lane == 0) { redg[w] = gterm; redm[w] = mcnt; }

    // ---- E column in registers: Ecol[m] = (exp(trans[2m][j]), exp(trans[2m+1][j])) fp16
    h2 Ecol[128];
    {
        const float* tc = trans + j;
        #pragma unroll
        for (int m = 0; m < 128; ++m) {
            float e0 = __expf(tc[(size_t)(2 * m) * T]);
            float e1 = __expf(tc[(size_t)(2 * m + 1) * T]);
            h2 v; v[0] = (_Float16)e0; v[1] = (_Float16)e1;
            Ecol[m] = v;
        }
    }

    // ---- initial wave max of vv -> redmax[0]
    float Mw = wave_max_bcast(vv);
    if (lane == 0) redmax[0][w] = Mw;

    __syncthreads();   // full drain once (also waits the primed tiles — fine)

    float gold = 0.f;
    if (j == 0) {
        const float g  = redg[0] + redg[1] + redg[2] + redg[3];
        const float mc = redm[0] + redm[1] + redm[2] + redm[3];
        const int seq_end = (int)mc - 1;
        gold = g + end_t[tags[seq_end * B + b]];
    }

    for (int t = 1; t < S; ++t) {
        // ---- phase B: issue early loads, write p scaled by OWN wave max (exact, in-register)
        const float4 rm = *(const float4*)&redmax[(t - 1) & 1][0];  // broadcast read; lands during GEMV
        const int mskt = msk[t];
        const float p = __expf(vv - Mw);            // p <= 1, fp16-safe
        pl[j] = (_Float16)p;
        if (t < S - 3) {
            const float* src = feats + ((size_t)(t + 3) * B + b) * T + j;
            __builtin_amdgcn_global_load_lds((const AS1 void*)src,
                                             (AS3 void*)&ftile[(t + 3) & 3][j], 4, 0, 0);
            asm volatile("s_waitcnt vmcnt(3)" ::: "memory");  // tile t landed (3-step slack)
        } else {
            asm volatile("s_waitcnt vmcnt(0)" ::: "memory");  // tail: drain (free, long landed)
        }
        const float ft = ftile[t & 3][j];           // own wave's quarter — own loads
        BAR();   // barrier 1: pl visible

        // ---- GEMV: 4 accumulators, one per 64-row wave region (own scale each)
        float a0 = 0.f, a1 = 0.f, a2 = 0.f, a3 = 0.f;
        const h8* pp = (const h8*)pl;
        #pragma unroll
        for (int r = 0; r < 8; ++r) {
            h8 pv = pp[r];
            a0 = FDOT2(Ecol[4 * r + 0], __builtin_shufflevector(pv, pv, 0, 1), a0);
            a0 = FDOT2(Ecol[4 * r + 1], __builtin_shufflevector(pv, pv, 2, 3), a0);
            a0 = FDOT2(Ecol[4 * r + 2], __builtin_shufflevector(pv, pv, 4, 5), a0);
            a0 = FDOT2(Ecol[4 * r + 3], __builtin_shufflevector(pv, pv, 6, 7), a0);
        }
        #pragma unroll
        for (int r = 8; r < 16; ++r) {
            h8 pv = pp[r];
            a1 = FDOT2(Ecol[4 * r + 0], __builtin_shufflevector(pv, pv, 0, 1), a1);
            a1 = FDOT2(Ecol[4 * r + 1], __builtin_shufflevector(pv, pv, 2, 3), a1);
            a1 = FDOT2(Ecol[4 * r + 2], __builtin_shufflevector(pv, pv, 4, 5), a1);
            a1 = FDOT2(Ecol[4 * r + 3], __builtin_shufflevector(pv, pv, 6, 7), a1);
        }
        #pragma unroll
        for (int r = 16; r < 24; ++r) {
            h8 pv = pp[r];
            a2 = FDOT2(Ecol[4 * r + 0], __builtin_shufflevector(pv, pv, 0, 1), a2);
            a2 = FDOT2(Ecol[4 * r + 1], __builtin_shufflevector(pv, pv, 2, 3), a2);
            a2 = FDOT2(Ecol[4 * r + 2], __builtin_shufflevector(pv, pv, 4, 5), a2);
            a2 = FDOT2(Ecol[4 * r + 3], __builtin_shufflevector(pv, pv, 6, 7), a2);
        }
        #pragma unroll
        for (int r = 24; r < 32; ++r) {
            h8 pv = pp[r];
            a3 = FDOT2(Ecol[4 * r + 0], __builtin_shufflevector(pv, pv, 0, 1), a3);
            a3 = FDOT2(Ecol[4 * r + 1], __builtin_shufflevector(pv, pv, 2, 3), a3);
            a3 = FDOT2(Ecol[4 * r + 2], __builtin_shufflevector(pv, pv, 4, 5), a3);
            a3 = FDOT2(Ecol[4 * r + 3], __builtin_shufflevector(pv, pv, 6, 7), a3);
        }

        // ---- phase D: per-wave rescale, log, masked update, DPP max (pure VALU)
        const float M = fmaxf(fmaxf(rm.x, rm.y), fmaxf(rm.z, rm.w));
        const float s = a0 * __expf(rm.x - M) + a1 * __expf(rm.y - M)
                      + a2 * __expf(rm.z - M) + a3 * __expf(rm.w - M);
        const float nxt = ft + M + __logf(s);
        vv = mskt ? nxt : vv;
        Mw = wave_max_bcast(vv);
        if (lane == 0) redmax[t & 1][w] = Mw;
        BAR();   // barrier 2: redmax/pl reusable
    }

    // ---- finalize: forward = logsumexp(vv + end_transitions) ; out = forward - gold
    const float u = vv + endj;
    const float mwu = wave_max_bcast(u);
    if (lane == 0) redmax[0][w] = mwu;
    BAR();
    {
        const float4 rm = *(const float4*)&redmax[0][0];
        const float M3 = fmaxf(fmaxf(rm.x, rm.y), fmaxf(rm.z, rm.w));
        float e = __expf(u - M3);
        #pragma unroll
        for (int o = 32; o > 0; o >>= 1) e += __shfl_xor(e, o, 64);
        if (lane == 0) redg[w] = e;
        BAR();
        if (j == 0) {
            out[b] = M3 + __logf(redg[0] + redg[1] + redg[2] + redg[3]) - gold;
        }
    }
}

extern "C" void kernel_launch(void* const* d_in, const int* in_sizes, int n_in,
                              void* d_out, int out_size, void* d_ws, size_t ws_size,
                              hipStream_t stream) {
    const float* feats  = (const float*)d_in[0];
    const int*   tags   = (const int*)d_in[1];
    const int*   mask   = (const int*)d_in[2];
    const float* startt = (const float*)d_in[3];
    const float* endt   = (const float*)d_in[4];
    const float* transt = (const float*)d_in[5];
    float* out = (float*)d_out;
    crf_fwd<<<dim3(B), dim3(NTH), 0, stream>>>(feats, tags, mask, startt, endt, transt, out);
}

// Round 4
// 366.952 us; speedup vs baseline: 1.3055x; 1.3055x over previous
//
#include <hip/hip_runtime.h>
#include <math.h>

#define S 512
#define B 128
#define T 256
#define NTH 256

typedef _Float16 h2 __attribute__((ext_vector_type(2)));

#if __has_builtin(__builtin_amdgcn_fdot2)
#define FDOT2(a, b, c) __builtin_amdgcn_fdot2((a), (b), (c), false)
#else
#define FDOT2(a, b, c) fmaf((float)(a)[0], (float)(b)[0], fmaf((float)(a)[1], (float)(b)[1], (c)))
#endif

// cvt_pkrtz returns __fp16 vector; bit_cast to our h2 (_Float16 vector)
#define PKRTZ(a, b) __builtin_bit_cast(h2, __builtin_amdgcn_cvt_pkrtz((a), (b)))

#define AS1 __attribute__((address_space(1)))
#define AS3 __attribute__((address_space(3)))

// LDS-drain barrier only (global prefetch ring stays in flight; counted vmcnt elsewhere)
#define BAR() do { asm volatile("s_waitcnt lgkmcnt(0)" ::: "memory"); __builtin_amdgcn_s_barrier(); } while (0)

// ---- DPP wave64 max reduction ----
template<int CTRL, int RM>
__device__ __forceinline__ float dppmax(float x) {
    int xi = __builtin_bit_cast(int, x);
    int yi = __builtin_amdgcn_update_dpp(xi, xi, CTRL, RM, 0xf, false);
    return fmaxf(x, __builtin_bit_cast(float, yi));
}
__device__ __forceinline__ float wave_max_bcast(float x) {
    x = dppmax<0x111, 0xf>(x);  // row_shr:1
    x = dppmax<0x112, 0xf>(x);  // row_shr:2
    x = dppmax<0x114, 0xf>(x);  // row_shr:4
    x = dppmax<0x118, 0xf>(x);  // row_shr:8
    x = dppmax<0x142, 0xa>(x);  // row_bcast:15
    x = dppmax<0x143, 0xc>(x);  // row_bcast:31
    return __builtin_bit_cast(float, __builtin_amdgcn_readlane(__builtin_bit_cast(int, x), 63));
}

// neighbor within quad: lane gets lane|1's value (sel [1,1,3,3] -> ctrl 0xF5)
__device__ __forceinline__ float quad_next(float x) {
    int xi = __builtin_bit_cast(int, x);
    int yi = __builtin_amdgcn_update_dpp(xi, xi, 0xF5, 0xf, 0xf, false);
    return __builtin_bit_cast(float, yi);
}

__global__ __launch_bounds__(NTH, 1) void crf_fwd(
    const float* __restrict__ feats,
    const int*   __restrict__ tags,
    const int*   __restrict__ mask,
    const float* __restrict__ start_t,
    const float* __restrict__ end_t,
    const float* __restrict__ trans,
    float*       __restrict__ out)
{
    const int b    = blockIdx.x;
    const int j    = threadIdx.x;     // owned state column 0..255
    const int lane = j & 63;
    const int w    = j >> 6;          // wave 0..3 (= i-group for GEMV)

    __shared__ __attribute__((aligned(16))) float part[2][4][T];  // partial sums, ping-pong
    __shared__ float ftile[4][T];                                 // feats prefetch ring
    __shared__ int   msk[S];
    __shared__ __attribute__((aligned(16))) float redmax[2][4];
    __shared__ float redg[4], redm[4];

    // ---- prime prefetch ring with feats tiles t=1..3
    #pragma unroll
    for (int tn = 1; tn <= 3; ++tn) {
        const float* src = feats + ((size_t)tn * B + b) * T + j;
        __builtin_amdgcn_global_load_lds((const AS1 void*)src,
                                         (AS3 void*)&ftile[tn & 3][j], 4, 0, 0);
    }

    // ---- small per-thread loads
    const float endj = end_t[j];
    float vv = start_t[j] + feats[(size_t)b * T + j];   // t=0
    msk[j]     = mask[j * B + b];
    msk[j + T] = mask[(j + T) * B + b];

    // ---- gold-score terms: two time steps per thread
    float gterm = 0.f, mcnt = 0.f;
    #pragma unroll
    for (int c = 0; c < 2; ++c) {
        const int t  = j + c * T;
        const int tg = tags[t * B + b];
        const int m  = mask[t * B + b];
        const float emit = feats[((size_t)t * B + b) * T + tg];
        mcnt += (float)m;
        if (t == 0) {
            gterm += start_t[tg] + emit;
        } else {
            gterm += m ? (emit + trans[tags[(t - 1) * B + b] * T + tg]) : 0.f;
        }
    }
    #pragma unroll
    for (int o = 32; o > 0; o >>= 1) {
        gterm += __shfl_down(gterm, o, 64);
        mcnt  += __shfl_down(mcnt, o, 64);
    }
    if (lane == 0) { redg[w] = gterm; redm[w] = mcnt; }

    // ---- E fragment in registers: rows i in [w*64, w*64+64), cols jc = lane*4+c
    // E2[ip][c] = ( exp(trans[w*64+2ip][jc]), exp(trans[w*64+2ip+1][jc]) ) as fp16 pair
    h2 E2[32][4];
    {
        const float* tp = trans + (size_t)(w * 64) * T + lane * 4;
        #pragma unroll
        for (int ip = 0; ip < 32; ++ip) {
            const float4 ra = *(const float4*)(tp + (size_t)(2 * ip) * T);
            const float4 rb = *(const float4*)(tp + (size_t)(2 * ip + 1) * T);
            E2[ip][0] = PKRTZ(__expf(ra.x), __expf(rb.x));
            E2[ip][1] = PKRTZ(__expf(ra.y), __expf(rb.y));
            E2[ip][2] = PKRTZ(__expf(ra.z), __expf(rb.z));
            E2[ip][3] = PKRTZ(__expf(ra.w), __expf(rb.w));
        }
    }

    // ---- initial wave max of vv -> redmax[0]
    float Mw = wave_max_bcast(vv);
    if (lane == 0) redmax[0][w] = Mw;

    __syncthreads();   // full drain once (init)

    float gold = 0.f;
    if (j == 0) {
        const float g  = redg[0] + redg[1] + redg[2] + redg[3];
        const float mc = redm[0] + redm[1] + redm[2] + redm[3];
        gold = g + end_t[tags[((int)mc - 1) * B + b]];
    }

    for (int t = 1; t < S; ++t) {
        // ---- pre-barrier: all in-wave (p never touches LDS)
        const int mskt = msk[t];                      // LDS broadcast, issued early
        const float p  = __expf(vv - Mw);             // own-wave scale, p <= 1
        const float pn = quad_next(p);
        const h2 pk    = PKRTZ(p, pn);                // even lanes hold (p[l], p[l+1])
        const int pki  = __builtin_bit_cast(int, pk);

        if (t < S - 3) {
            const float* src = feats + ((size_t)(t + 3) * B + b) * T + j;
            __builtin_amdgcn_global_load_lds((const AS1 void*)src,
                                             (AS3 void*)&ftile[(t + 3) & 3][j], 4, 0, 0);
            asm volatile("s_waitcnt vmcnt(3)" ::: "memory");
        } else {
            asm volatile("s_waitcnt vmcnt(0)" ::: "memory");
        }
        const float ft = ftile[t & 3][j];             // own element (own DMA load)

        // ---- GEMV over own wave's 64 i-rows: p pairs broadcast via v_readlane (SGPR operand)
        float ax = 0.f, ay = 0.f, az = 0.f, aw = 0.f;
        int pr0 = __builtin_amdgcn_readlane(pki, 0);
        #pragma unroll
        for (int ip = 0; ip < 32; ++ip) {
            const int pr1 = (ip < 31) ? __builtin_amdgcn_readlane(pki, 2 * ip + 2) : 0;
            const h2 pp = __builtin_bit_cast(h2, pr0);
            ax = FDOT2(E2[ip][0], pp, ax);
            ay = FDOT2(E2[ip][1], pp, ay);
            az = FDOT2(E2[ip][2], pp, az);
            aw = FDOT2(E2[ip][3], pp, aw);
            pr0 = pr1;
        }
        {
            float4 acc; acc.x = ax; acc.y = ay; acc.z = az; acc.w = aw;
            *(float4*)&part[t & 1][w][lane * 4] = acc;   // partials for cols lane*4..+3
        }
        BAR();   // the ONLY barrier per step

        // ---- post-barrier: combine 4 i-group partials with exact rescale
        const float4 rm = *(const float4*)&redmax[(t - 1) & 1][0];
        const float s0 = part[t & 1][0][j];
        const float s1 = part[t & 1][1][j];
        const float s2 = part[t & 1][2][j];
        const float s3 = part[t & 1][3][j];
        const float M  = fmaxf(fmaxf(rm.x, rm.y), fmaxf(rm.z, rm.w));
        const float s  = s0 * __expf(rm.x - M) + s1 * __expf(rm.y - M)
                       + s2 * __expf(rm.z - M) + s3 * __expf(rm.w - M);
        const float nxt = ft + M + __logf(s);
        vv = mskt ? nxt : vv;
        Mw = wave_max_bcast(vv);
        if (lane == 0) redmax[t & 1][w] = Mw;
        // no trailing barrier: next step's cross-wave reads happen after ITS barrier
    }

    BAR();   // protect final redmax reuse against last iteration's readers

    // ---- finalize: forward = logsumexp(vv + end_transitions); out = forward - gold
    const float u = vv + endj;
    const float mwu = wave_max_bcast(u);
    if (lane == 0) redmax[0][w] = mwu;
    BAR();
    {
        const float4 rm = *(const float4*)&redmax[0][0];
        const float M3 = fmaxf(fmaxf(rm.x, rm.y), fmaxf(rm.z, rm.w));
        float e = __expf(u - M3);
        #pragma unroll
        for (int o = 32; o > 0; o >>= 1) e += __shfl_xor(e, o, 64);
        if (lane == 0) redg[w] = e;
        BAR();
        if (j == 0) {
            out[b] = M3 + __logf(redg[0] + redg[1] + redg[2] + redg[3]) - gold;
        }
    }
}

extern "C" void kernel_launch(void* const* d_in, const int* in_sizes, int n_in,
                              void* d_out, int out_size, void* d_ws, size_t ws_size,
                              hipStream_t stream) {
    const float* feats  = (const float*)d_in[0];
    const int*   tags   = (const int*)d_in[1];
    const int*   mask   = (const int*)d_in[2];
    const float* startt = (const float*)d_in[3];
    const float* endt   = (const float*)d_in[4];
    const float* transt = (const float*)d_in[5];
    float* out = (float*)d_out;
    crf_fwd<<<dim3(B), dim3(NTH), 0, stream>>>(feats, tags, mask, startt, endt, transt, out);
}

// Round 5
// 326.599 us; speedup vs baseline: 1.4668x; 1.1236x over previous
//
#include <hip/hip_runtime.h>
#include <math.h>

#define S 512
#define B 128
#define T 256
#define NTH 256
#define LOG2E 1.44269504f
#define LN2 0.69314718f

typedef _Float16 h2 __attribute__((ext_vector_type(2)));

#if __has_builtin(__builtin_amdgcn_fdot2)
#define FDOT2(a, b, c) __builtin_amdgcn_fdot2((a), (b), (c), false)
#else
#define FDOT2(a, b, c) fmaf((float)(a)[0], (float)(b)[0], fmaf((float)(a)[1], (float)(b)[1], (c)))
#endif

// cvt_pkrtz returns __fp16 vector; bit_cast to our h2
#define PKRTZ(a, b) __builtin_bit_cast(h2, __builtin_amdgcn_cvt_pkrtz((a), (b)))

#define AS1 __attribute__((address_space(1)))
#define AS3 __attribute__((address_space(3)))

// LDS-drain barrier only (global DMA ring stays in flight; counted vmcnt elsewhere)
#define BAR() do { asm volatile("s_waitcnt lgkmcnt(0)" ::: "memory"); __builtin_amdgcn_s_barrier(); } while (0)

// exact x * 2^n for n in [-126,127] (branchless, no denorm corner: |n| stays small here)
__device__ __forceinline__ float mul2n(float x, int n) {
    return x * __builtin_bit_cast(float, (n + 127) << 23);
}

// ---- DPP wave64 max reduction ----
template<int CTRL, int RM>
__device__ __forceinline__ float dppmax(float x) {
    int xi = __builtin_bit_cast(int, x);
    int yi = __builtin_amdgcn_update_dpp(xi, xi, CTRL, RM, 0xf, false);
    return fmaxf(x, __builtin_bit_cast(float, yi));
}
__device__ __forceinline__ float wave_max_bcast(float x) {
    x = dppmax<0x111, 0xf>(x);  // row_shr:1
    x = dppmax<0x112, 0xf>(x);  // row_shr:2
    x = dppmax<0x114, 0xf>(x);  // row_shr:4
    x = dppmax<0x118, 0xf>(x);  // row_shr:8
    x = dppmax<0x142, 0xa>(x);  // row_bcast:15
    x = dppmax<0x143, 0xc>(x);  // row_bcast:31
    return __builtin_bit_cast(float, __builtin_amdgcn_readlane(__builtin_bit_cast(int, x), 63));
}

// lane gets lane|1's value within each quad (sel [1,1,3,3] -> 0xF5)
__device__ __forceinline__ float quad_next(float x) {
    int xi = __builtin_bit_cast(int, x);
    int yi = __builtin_amdgcn_update_dpp(xi, xi, 0xF5, 0xf, 0xf, false);
    return __builtin_bit_cast(float, yi);
}

__global__ __launch_bounds__(NTH, 1) void crf_fwd(
    const float* __restrict__ feats,
    const int*   __restrict__ tags,
    const int*   __restrict__ mask,
    const float* __restrict__ start_t,
    const float* __restrict__ end_t,
    const float* __restrict__ trans,
    float*       __restrict__ out)
{
    const int b    = blockIdx.x;
    const int j    = threadIdx.x;     // owned state column 0..255
    const int lane = j & 63;
    const int w    = j >> 6;          // wave 0..3 (= row-group for GEMV)

    __shared__ __attribute__((aligned(16))) float part[2][4][T];  // partials, ping-pong
    __shared__ float ftile[4][T];                                 // feats DMA ring
    __shared__ int   msk[S];
    __shared__ __attribute__((aligned(16))) int Aex[2][4];        // per-wave exponents, ping-pong
    __shared__ float redmax[4], redg[4], redm[4];

    // ---- prime DMA ring with feats tiles t=1..3
    #pragma unroll
    for (int tn = 1; tn <= 3; ++tn) {
        const float* src = feats + ((size_t)tn * B + b) * T + j;
        __builtin_amdgcn_global_load_lds((const AS1 void*)src,
                                         (AS3 void*)&ftile[tn & 3][j], 4, 0, 0);
    }

    // ---- small per-thread loads
    const float endj = end_t[j];
    const float sc0  = start_t[j] + feats[(size_t)b * T + j];   // score at t=0
    msk[j]     = mask[j * B + b];
    msk[j + T] = mask[(j + T) * B + b];

    // ---- gold-score terms: two time steps per thread
    float gterm = 0.f, mcnt = 0.f;
    #pragma unroll
    for (int c = 0; c < 2; ++c) {
        const int t  = j + c * T;
        const int tg = tags[t * B + b];
        const int m  = mask[t * B + b];
        const float emit = feats[((size_t)t * B + b) * T + tg];
        mcnt += (float)m;
        if (t == 0) {
            gterm += start_t[tg] + emit;
        } else {
            gterm += m ? (emit + trans[tags[(t - 1) * B + b] * T + tg]) : 0.f;
        }
    }
    #pragma unroll
    for (int o = 32; o > 0; o >>= 1) {
        gterm += __shfl_down(gterm, o, 64);
        mcnt  += __shfl_down(mcnt, o, 64);
    }
    if (lane == 0) { redg[w] = gterm; redm[w] = mcnt; }

    // ---- E fragment (RTN packing): rows i in [w*64, w*64+64), cols lane*4+c
    h2 E2[32][4];
    {
        const float* tp = trans + (size_t)(w * 64) * T + lane * 4;
        #pragma unroll
        for (int ip = 0; ip < 32; ++ip) {
            const float4 ra = *(const float4*)(tp + (size_t)(2 * ip) * T);
            const float4 rb = *(const float4*)(tp + (size_t)(2 * ip + 1) * T);
            #pragma unroll
            for (int c = 0; c < 4; ++c) {
                const float e0 = __expf(c == 0 ? ra.x : c == 1 ? ra.y : c == 2 ? ra.z : ra.w);
                const float e1 = __expf(c == 0 ? rb.x : c == 1 ? rb.y : c == 2 ? rb.z : rb.w);
                h2 v; v[0] = (_Float16)e0; v[1] = (_Float16)e1;
                E2[ip][c] = v;
            }
        }
    }

    // ---- linear-state init: q = exp(sc0)*2^-A, target max ~2^-10
    float mq0 = wave_max_bcast(sc0);
    int A = (int)ceilf(mq0 * LOG2E) + 10;          // per-wave exponent accumulator
    float q = exp2f(fmaf(sc0, LOG2E, (float)(-A)));
    if (lane == 0) Aex[0][w] = A;
    // k for step 1 (stale max of q)
    float mq = wave_max_bcast(q);
    int k = ((__builtin_bit_cast(int, mq) >> 23) & 0xff) - 117;   // exp(mq) - 127 + 10
    // pack qhat for first GEMV
    int pki = __builtin_bit_cast(int, PKRTZ(q, quad_next(q)));

    __syncthreads();   // full drain once (init)

    float gold = 0.f;
    if (j == 0) {
        const float g  = redg[0] + redg[1] + redg[2] + redg[3];
        const float mc = redm[0] + redm[1] + redm[2] + redm[3];
        gold = g + end_t[tags[((int)mc - 1) * B + b]];
    }

    for (int t = 1; t < S; ++t) {
        // ---- GEMV over own wave's 64 rows (qhat pairs broadcast via readlane)
        float ax = 0.f, ay = 0.f, az = 0.f, aw = 0.f;
        int pr0 = __builtin_amdgcn_readlane(pki, 0);
        #pragma unroll
        for (int ip = 0; ip < 32; ++ip) {
            const int pr1 = (ip < 31) ? __builtin_amdgcn_readlane(pki, 2 * ip + 2) : 0;
            const h2 pp = __builtin_bit_cast(h2, pr0);
            ax = FDOT2(E2[ip][0], pp, ax);
            ay = FDOT2(E2[ip][1], pp, ay);
            az = FDOT2(E2[ip][2], pp, az);
            aw = FDOT2(E2[ip][3], pp, aw);
            pr0 = pr1;
        }
        {
            float4 acc; acc.x = ax; acc.y = ay; acc.z = az; acc.w = aw;
            *(float4*)&part[t & 1][w][lane * 4] = acc;
        }
        // ---- DMA ring
        if (t < S - 3) {
            const float* src = feats + ((size_t)(t + 3) * B + b) * T + j;
            __builtin_amdgcn_global_load_lds((const AS1 void*)src,
                                             (AS3 void*)&ftile[(t + 3) & 3][j], 4, 0, 0);
            asm volatile("s_waitcnt vmcnt(3)" ::: "memory");   // tile t landed
        } else {
            asm volatile("s_waitcnt vmcnt(0)" ::: "memory");
        }
        BAR();   // the only barrier per step

        // ---- combine (no log, no exp of state; power-of-2 scales exact)
        const int4  Av = *(const int4*)&Aex[(t - 1) & 1][0];   // broadcast
        const float s0 = part[t & 1][0][j];
        const float s1 = part[t & 1][1][j];
        const float s2 = part[t & 1][2][j];
        const float s3 = part[t & 1][3][j];
        const float ft = ftile[t & 3][j];
        const int mskt = msk[t];
        const int a0 = __builtin_amdgcn_readfirstlane(Av.x);
        const int a1 = __builtin_amdgcn_readfirstlane(Av.y);
        const int a2 = __builtin_amdgcn_readfirstlane(Av.z);
        const int a3 = __builtin_amdgcn_readfirstlane(Av.w);
        const float cb = mul2n(s0, a0 - A) + mul2n(s1, a1 - A)
                       + mul2n(s2, a2 - A) + mul2n(s3, a3 - A);
        const float F  = exp2f(fmaf(ft, LOG2E, (float)(-k)));   // exp(ft)*2^-k
        const float qn = cb * F;
        const float qf = mul2n(q, -k);                          // frozen path (mask=0)
        q = mskt ? qn : qf;
        A += k;
        if (lane == 0) Aex[t & 1][w] = A;
        // next k from this q's max (off critical path: used next step)
        mq = wave_max_bcast(q);
        k = ((__builtin_bit_cast(int, mq) >> 23) & 0xff) - 117;
        // pack for next GEMV
        pki = __builtin_bit_cast(int, PKRTZ(q, quad_next(q)));
    }

    BAR();

    // ---- finalize: score_j = (log2(q)+A)*ln2 ; forward = LSE(score + end)
    const float u2 = __log2f(q) + (float)A + endj * LOG2E;      // log2-domain
    const float m2w = wave_max_bcast(u2);
    if (lane == 0) redmax[w] = m2w;
    BAR();
    {
        const float M2 = fmaxf(fmaxf(redmax[0], redmax[1]), fmaxf(redmax[2], redmax[3]));
        float e = exp2f(u2 - M2);
        #pragma unroll
        for (int o = 32; o > 0; o >>= 1) e += __shfl_xor(e, o, 64);
        if (lane == 0) redg[w] = e;
        BAR();
        if (j == 0) {
            out[b] = (M2 + __log2f(redg[0] + redg[1] + redg[2] + redg[3])) * LN2 - gold;
        }
    }
}

extern "C" void kernel_launch(void* const* d_in, const int* in_sizes, int n_in,
                              void* d_out, int out_size, void* d_ws, size_t ws_size,
                              hipStream_t stream) {
    const float* feats  = (const float*)d_in[0];
    const int*   tags   = (const int*)d_in[1];
    const int*   mask   = (const int*)d_in[2];
    const float* startt = (const float*)d_in[3];
    const float* endt   = (const float*)d_in[4];
    const float* transt = (const float*)d_in[5];
    float* out = (float*)d_out;
    crf_fwd<<<dim3(B), dim3(NTH), 0, stream>>>(feats, tags, mask, startt, endt, transt, out);
}